// Round 4
// baseline (1081.379 us; speedup 1.0000x reference)
//
#include <hip/hip_runtime.h>

typedef float v4f __attribute__((ext_vector_type(4)));

// Problem constants (from reference)
constexpr int B = 256;        // batch
constexpr int T = 64;         // trees
constexpr int C = 1000;       // mask columns (idx domain)
constexpr int F = 16080;      // output feature width
constexpr int K = 200;        // top-k
constexpr int F4 = F / 4;     // 4020 float4 per row
constexpr int C4 = C / 4;     // 250 float4 with possible nonzeros
constexpr unsigned N4 = (unsigned)B * T * F4;   // 65,863,680 quads in return_value
constexpr unsigned FILL_BLOCKS = N4 / 1024;     // 64,320 exactly (no remainder)

// Kernel 1: one block per tree. Zero the attention row, find top-200 of the
// mask row via bitonic sort of packed keys in LDS, scatter sigmoid values.
// Key = (monotone(float_bits) << 32) | ~index  -> descending sort gives
// values descending, ties broken by lower index (matches lax.top_k).
__global__ __launch_bounds__(256) void topk_scatter_kernel(
    const float* __restrict__ mask, float* __restrict__ attn) {
  const int t = blockIdx.x;
  const int tid = threadIdx.x;
  __shared__ unsigned long long keys[1024];

  const float* row = mask + (size_t)t * C;
  float* arow = attn + (size_t)t * F;

  for (int i = tid; i < 1024; i += 256) {
    if (i < C) {
      unsigned ub = __float_as_uint(row[i]);
      unsigned mono = (ub & 0x80000000u) ? ~ub : (ub | 0x80000000u);
      keys[i] = ((unsigned long long)mono << 32) | (unsigned)(~i);
    } else {
      keys[i] = 0ull;
    }
  }
  // zero the attention output row (vectorized) while keys land
  {
    v4f* arow4 = (v4f*)arow;
    const v4f z = {0.0f, 0.0f, 0.0f, 0.0f};
    for (int i = tid; i < F4; i += 256) arow4[i] = z;
  }
  __syncthreads();

  // bitonic sort, descending
  for (int k = 2; k <= 1024; k <<= 1) {
    for (int j = k >> 1; j > 0; j >>= 1) {
      for (int ii = tid; ii < 1024; ii += 256) {
        int l = ii ^ j;
        if (l > ii) {
          unsigned long long a = keys[ii];
          unsigned long long b2 = keys[l];
          bool sw = ((ii & k) == 0) ? (a < b2) : (a > b2);
          if (sw) { keys[ii] = b2; keys[l] = a; }
        }
      }
      __syncthreads();
    }
  }

  if (tid < K) {
    unsigned long long key = keys[tid];
    unsigned idx = ~(unsigned)(key & 0xFFFFFFFFull);
    unsigned mono = (unsigned)(key >> 32);
    unsigned bits = (mono & 0x80000000u) ? (mono ^ 0x80000000u) : ~mono;
    float v = __uint_as_float(bits);
    float s = 1.0f / (1.0f + expf(-v));
    arow[idx] = s;
  }
}

// Kernel 2: pure zero-fill of the whole return_value region — an exact clone
// of the rocclr fill kernel's store stream (which hits 79% of HBM peak on
// this very buffer). No loops, no divisions, no branches, no loads: each
// block covers 1024 consecutive quads (16 KB), each thread issues 4
// independent dwordx4 stores. N4 = 64320 * 1024 exactly.
__global__ __launch_bounds__(256) void zero_fill_kernel(float* __restrict__ out) {
  v4f* o4 = (v4f*)out + (size_t)blockIdx.x * 1024u + threadIdx.x;
  const v4f z = {0.0f, 0.0f, 0.0f, 0.0f};
  o4[0]   = z;
  o4[256] = z;
  o4[512] = z;
  o4[768] = z;
}

// Kernel 3: overwrite only the potentially-nonzero region: cols [0,1000) of
// each (b,t) row. One block per row, tid<250 active: 2 loads (L2-resident
// after first touch: x slice 1 MB, attn slice 64 KB) + 1 store. 65.5 MB.
__global__ __launch_bounds__(256) void product_kernel(
    const float* __restrict__ x, const float* __restrict__ attn,
    float* __restrict__ out) {
  const int p = blockIdx.x;       // p = b*64 + t
  const int tid = threadIdx.x;
  if (tid >= C4) return;
  const v4f* x4 = (const v4f*)(x + (size_t)(p >> 6) * F);
  const v4f* a4 = (const v4f*)(attn + (size_t)(p & 63) * F);
  v4f* o4 = (v4f*)(out + (size_t)p * F);
  o4[tid] = x4[tid] * a4[tid];
}

extern "C" void kernel_launch(void* const* d_in, const int* in_sizes, int n_in,
                              void* d_out, int out_size, void* d_ws, size_t ws_size,
                              hipStream_t stream) {
  const float* x = (const float*)d_in[0];          // (256,120,134) -> (256,16080)
  const float* mask = (const float*)d_in[1];       // (64,1000)
  float* out = (float*)d_out;                      // return_value (256,64,16080)
  float* attn = out + (size_t)B * T * F;           // attention (64,16080), 2nd output

  topk_scatter_kernel<<<T, 256, 0, stream>>>(mask, attn);
  zero_fill_kernel<<<FILL_BLOCKS, 256, 0, stream>>>(out);
  // stream order guarantees: fill's zeros land before product overwrites
  // the [0,1000) stripe, and topk's attn is visible to product.
  product_kernel<<<B * T, 256, 0, stream>>>(x, attn, out);
}